// Round 3
// baseline (527.333 us; speedup 1.0000x reference)
//
#include <hip/hip_runtime.h>

#define NUM_USER  200000
#define NUM_GROUP 50000
#define NN        (NUM_USER + NUM_GROUP)   // 250000
#define E_EDGES   4000000
#define D         64
#define B         8192

#define BSHIFT       10                                     // 1024 rows / bucket
#define NB_BUCKETS   ((NN + (1 << BSHIFT) - 1) >> BSHIFT)   // 245
#define CHUNK_EDGES  4096                                   // edges per phase-A block
#define PB_THREADS   1024                                   // phase-B block size

#define CSHIFT       15                                     // 32768 cols / chunk (4 MB of x)
#define NCHUNK       8                                      // 250000 >> 15 -> 0..7

// --- bf16 helpers (RNE; values are normal floats, no NaN path needed) ------
__device__ __forceinline__ float bf2f(unsigned short u) {
    return __uint_as_float(((unsigned int)u) << 16);
}
__device__ __forceinline__ unsigned short f2bf(float f) {
    unsigned int x = __float_as_uint(f);
    return (unsigned short)((x + 0x7FFFu + ((x >> 16) & 1u)) >> 16);
}
// packed-bf16 dword -> two floats (lo = even dim, hi = odd dim)
__device__ __forceinline__ float bflo(unsigned int u) { return __uint_as_float(u << 16); }
__device__ __forceinline__ float bfhi(unsigned int u) { return __uint_as_float(u & 0xFFFF0000u); }

// ---------------------------------------------------------------------------
// Convert concat(user_table, group_table) fp32 -> bf16 emb0 (vectorized x4)
// ---------------------------------------------------------------------------
__global__ void __launch_bounds__(256)
convert_tables(const float* __restrict__ ut,
               const float* __restrict__ gt,
               unsigned short* __restrict__ embT) {
    const long long total4 = (long long)NN * D / 4;
    const long long user4  = (long long)NUM_USER * D / 4;
    long long i = (long long)blockIdx.x * blockDim.x + threadIdx.x;
    if (i >= total4) return;
    float4 v = (i < user4) ? ((const float4*)ut)[i] : ((const float4*)gt)[i - user4];
    ushort4 o;
    o.x = f2bf(v.x); o.y = f2bf(v.y); o.z = f2bf(v.z); o.w = f2bf(v.w);
    ((ushort4*)embT)[i] = o;
}

// ---------------------------------------------------------------------------
// Bucket histogram: LDS-aggregated 245-counter histogram per 4096-edge block,
// then ONE global atomic per (block, nonempty bucket).
// ---------------------------------------------------------------------------
__global__ void __launch_bounds__(256)
bucket_hist(const int* __restrict__ rows, int* __restrict__ bucketCounts) {
    __shared__ int cnt[NB_BUCKETS];
    const int t = threadIdx.x;
    if (t < NB_BUCKETS) cnt[t] = 0;
    __syncthreads();
    const int base = blockIdx.x * CHUNK_EDGES;
    #pragma unroll
    for (int k = 0; k < CHUNK_EDGES / 256; ++k) {
        int e = base + t + k * 256;
        if (e < E_EDGES) atomicAdd(&cnt[rows[e] >> BSHIFT], 1);
    }
    __syncthreads();
    if (t < NB_BUCKETS && cnt[t] > 0) atomicAdd(&bucketCounts[t], cnt[t]);
}

// ---------------------------------------------------------------------------
// Scan of the 245 bucket counts (single small block):
//   bucketPtr[b] = exclusive prefix, bucketPtr[245] = E,
//   cursorA[b]   = staging cursor init,
//   row_ptr[NN]  = E (per-row entries are written by phase B).
// ---------------------------------------------------------------------------
__global__ void __launch_bounds__(256)
bucket_scan(const int* __restrict__ bucketCounts,
            int* __restrict__ bucketPtr,
            int* __restrict__ cursorA,
            int* __restrict__ row_ptr) {
    __shared__ int s[256];
    const int t = threadIdx.x;
    int v = (t < NB_BUCKETS) ? bucketCounts[t] : 0;
    s[t] = v;
    __syncthreads();
    for (int off = 1; off < 256; off <<= 1) {
        int u = (t >= off) ? s[t - off] : 0;
        __syncthreads();
        s[t] += u;
        __syncthreads();
    }
    int excl = s[t] - v;
    if (t < NB_BUCKETS) { bucketPtr[t] = excl; cursorA[t] = excl; }
    if (t == 255) {
        bucketPtr[NB_BUCKETS] = s[255];   // == E
        row_ptr[NN] = s[255];
    }
}

// ---------------------------------------------------------------------------
// Phase A: LDS-aggregated bucket append (parallel cursor reservation,
// 16-lane subgroup copy-out).
// Staged element: { (row_in_bucket << 18) | col, bits(val) }.
// ---------------------------------------------------------------------------
__global__ void __launch_bounds__(256)
bucket_phaseA(const int*   __restrict__ rows,
              const int*   __restrict__ cols,
              const float* __restrict__ vals,
              int*         __restrict__ cursorA,
              int2*        __restrict__ stage) {
    __shared__ int  cnt[256];
    __shared__ int  off[256];
    __shared__ int  cur[256];
    __shared__ int  gbase[256];
    __shared__ int2 stg[CHUNK_EDGES];    // 32 KB
    const int t = threadIdx.x;
    cnt[t] = 0;
    __syncthreads();

    const int base = blockIdx.x * CHUNK_EDGES;
    int re[CHUNK_EDGES / 256];           // cache rows -> no second global read
    #pragma unroll
    for (int k = 0; k < CHUNK_EDGES / 256; ++k) {
        int e = base + t + k * 256;
        re[k] = (e < E_EDGES) ? rows[e] : -1;
        if (re[k] >= 0) atomicAdd(&cnt[re[k] >> BSHIFT], 1);
    }
    __syncthreads();

    // exclusive scan of cnt -> off (Hillis-Steele over 256)
    int v = cnt[t];
    off[t] = v;
    __syncthreads();
    for (int o = 1; o < 256; o <<= 1) {
        int u = (t >= o) ? off[t - o] : 0;
        __syncthreads();
        off[t] += u;
        __syncthreads();
    }
    int excl = off[t] - v;
    __syncthreads();
    off[t] = excl;
    cur[t] = excl;
    // parallel cursor reservation: one independent atomic per bucket
    if (t < NB_BUCKETS && v > 0) gbase[t] = atomicAdd(&cursorA[t], v);
    __syncthreads();

    // place into LDS staging
    #pragma unroll
    for (int k = 0; k < CHUNK_EDGES / 256; ++k) {
        int r = re[k];
        if (r >= 0) {
            int e = base + t + k * 256;
            int b = r >> BSHIFT;
            int slot = atomicAdd(&cur[b], 1);
            stg[slot] = make_int2(((r & ((1 << BSHIFT) - 1)) << 18) | cols[e],
                                  __float_as_int(vals[e]));
        }
    }
    __syncthreads();

    // copy runs out: 16-lane subgroups (mean run length ~17), no atomics here
    const int sg = t >> 4;    // 0..15
    const int sl = t & 15;
    for (int b = sg; b < NB_BUCKETS; b += 16) {
        int n = cnt[b];
        if (n == 0) continue;
        int gb = gbase[b];
        int lb = off[b];
        for (int i = sl; i < n; i += 16)
            stage[gb + i] = stg[lb + i];
    }
}

// ---------------------------------------------------------------------------
// Phase B: ONE block (1024 threads) per bucket.
//   pass 1: LDS histogram over (row-in-bucket, col-chunk)  [1024 x 8]
//   scan  : 8192-wide LDS exclusive scan (chunk-minor) -> per-(row,chunk)
//           cursors; row_ptr = cursor of (row, chunk 0)
//   pass 2: exact CSR placement -- each row's edges land sorted by col-chunk.
// Col-chunk sorting makes every SpMM wave sweep x in the same 4 MB-chunk
// order, collapsing the gather working set to ~1 chunk per XCD L2.
// ---------------------------------------------------------------------------
__global__ void __launch_bounds__(PB_THREADS)
bucket_phaseB(const int*  __restrict__ bucketPtr,
              const int2* __restrict__ stage,
              int2*       __restrict__ pairs,
              int*        __restrict__ row_ptr) {
    __shared__ int cnt[(1 << BSHIFT) * NCHUNK];   // 8192 counts -> cursors (32 KB)
    __shared__ int tsum[PB_THREADS];              // block-scan workspace (4 KB)
    const int b = blockIdx.x;
    const int rowBase = b << BSHIFT;
    const int nRows = (NN - rowBase < (1 << BSHIFT)) ? (NN - rowBase) : (1 << BSHIFT);
    const int t = threadIdx.x;
    #pragma unroll
    for (int k = 0; k < NCHUNK; ++k) cnt[t + k * PB_THREADS] = 0;
    __syncthreads();

    const int s = bucketPtr[b];
    const int e = bucketPtr[b + 1];

    // pass 1: count (row-in-bucket, chunk)
    for (int i = s + t; i < e; i += PB_THREADS) {
        int px = stage[i].x;
        int rib = px >> 18;
        int chk = (px & 0x3FFFF) >> CSHIFT;
        atomicAdd(&cnt[(rib << 3) | chk], 1);
    }
    __syncthreads();

    // exclusive scan over 8192 entries: 8 serial per thread + 1024 block scan
    const int base8 = t << 3;
    int c[NCHUNK];
    int run = 0;
    #pragma unroll
    for (int k = 0; k < NCHUNK; ++k) {
        int tmp = cnt[base8 + k];
        c[k] = run;                      // exclusive within thread
        run += tmp;
    }
    tsum[t] = run;
    __syncthreads();
    for (int o = 1; o < PB_THREADS; o <<= 1) {
        int u = (t >= o) ? tsum[t - o] : 0;
        __syncthreads();
        tsum[t] += u;
        __syncthreads();
    }
    int texcl = tsum[t] - run;
    #pragma unroll
    for (int k = 0; k < NCHUNK; ++k)
        cnt[base8 + k] = s + texcl + c[k];     // absolute cursors
    __syncthreads();

    // emit row_ptr for this bucket (cursor of chunk 0 = row start)
    if (t < nRows) row_ptr[rowBase + t] = cnt[t << 3];
    __syncthreads();

    // pass 2: exact placement, chunk-sorted within each row
    for (int i = s + t; i < e; i += PB_THREADS) {
        int2 p = stage[i];
        int rib = p.x >> 18;
        int col = p.x & 0x3FFFF;
        int slot = atomicAdd(&cnt[(rib << 3) | (col >> CSHIFT)], 1);
        pairs[slot] = make_int2(col, p.y);
    }
}

// ---------------------------------------------------------------------------
// Pull-mode SpMM over bf16 embeddings: one wave per destination row.
// Quarter-wave edge parallelism: 4 edges in flight, each handled by a
// 16-lane quarter; lane covers 4 dims via one 8-byte uint2 load.
// Unroll x2 -> 8 edges / 4 vmem instructions per wave-iteration.
// Cross-quarter reduction: 2x shfl_xor per row. fp32 acc, bf16 store.
// ---------------------------------------------------------------------------
__global__ void __launch_bounds__(256)
spmm_pull_bf(const int*  __restrict__ row_ptr,
             const int2* __restrict__ pairs,
             const unsigned short* __restrict__ x,
             unsigned short*       __restrict__ y) {
    const int row  = blockIdx.x * 4 + (threadIdx.x >> 6);   // 4 waves / block
    if (row >= NN) return;
    const int lane = threadIdx.x & 63;
    const int sub  = lane >> 4;          // quarter id 0..3 (edge slot)
    const int sl   = lane & 15;          // dims 4*sl .. 4*sl+3
    const int start = row_ptr[row];
    const int end   = row_ptr[row + 1];

    float a0 = 0.f, a1 = 0.f, a2 = 0.f, a3 = 0.f;
    int e = start + sub;                 // this quarter's edge ptr, stride 4
    for (; e + 4 < end; e += 8) {
        int2 p0 = pairs[e];
        int2 p1 = pairs[e + 4];
        uint2 u0 = *(const uint2*)(x + (unsigned)(p0.x * D + 4 * sl));
        uint2 u1 = *(const uint2*)(x + (unsigned)(p1.x * D + 4 * sl));
        float v0 = __int_as_float(p0.y);
        float v1 = __int_as_float(p1.y);
        a0 += v0 * bflo(u0.x); a1 += v0 * bfhi(u0.x);
        a2 += v0 * bflo(u0.y); a3 += v0 * bfhi(u0.y);
        a0 += v1 * bflo(u1.x); a1 += v1 * bfhi(u1.x);
        a2 += v1 * bflo(u1.y); a3 += v1 * bfhi(u1.y);
    }
    if (e < end) {                       // <=1 remaining edge per quarter
        int2 p = pairs[e];
        uint2 u = *(const uint2*)(x + (unsigned)(p.x * D + 4 * sl));
        float v = __int_as_float(p.y);
        a0 += v * bflo(u.x); a1 += v * bfhi(u.x);
        a2 += v * bflo(u.y); a3 += v * bfhi(u.y);
    }
    // combine the 4 quarters (same dims live at same sl in every quarter)
    a0 += __shfl_xor(a0, 16); a0 += __shfl_xor(a0, 32);
    a1 += __shfl_xor(a1, 16); a1 += __shfl_xor(a1, 32);
    a2 += __shfl_xor(a2, 16); a2 += __shfl_xor(a2, 32);
    a3 += __shfl_xor(a3, 16); a3 += __shfl_xor(a3, 32);
    if (sub == 0) {
        ushort4 o;
        o.x = f2bf(a0); o.y = f2bf(a1); o.z = f2bf(a2); o.w = f2bf(a3);
        *(ushort4*)(y + (unsigned)(row * D + 4 * sl)) = o;
    }
}

// ---------------------------------------------------------------------------
// Final level, output-sparse: one wave per OUTPUT SLOT (3*B slots), same
// quarter-wave structure as spmm_pull_bf; adds 0.25*sum into d_out.
// ---------------------------------------------------------------------------
__global__ void __launch_bounds__(256)
final_pull(const int*  __restrict__ row_ptr,
           const int2* __restrict__ pairs,
           const unsigned short* __restrict__ x,      // emb2 bf16
           const int*  __restrict__ ui,
           const int*  __restrict__ pg,
           const int*  __restrict__ ng,
           float*      __restrict__ out) {
    const int slot = blockIdx.x * 4 + (threadIdx.x >> 6);   // 0 .. 3*B-1
    if (slot >= 3 * B) return;
    const int lane = threadIdx.x & 63;
    const int sub  = lane >> 4;
    const int sl   = lane & 15;
    const int region = slot / B;                 // 0=user, 1=pos, 2=neg
    const int b      = slot - region * B;
    int row;
    if (region == 0)      row = ui[b];
    else if (region == 1) row = NUM_USER + pg[b];
    else                  row = NUM_USER + ng[b];

    const int start = row_ptr[row];
    const int end   = row_ptr[row + 1];
    float a0 = 0.f, a1 = 0.f, a2 = 0.f, a3 = 0.f;
    int e = start + sub;
    for (; e + 4 < end; e += 8) {
        int2 p0 = pairs[e];
        int2 p1 = pairs[e + 4];
        uint2 u0 = *(const uint2*)(x + (unsigned)(p0.x * D + 4 * sl));
        uint2 u1 = *(const uint2*)(x + (unsigned)(p1.x * D + 4 * sl));
        float v0 = __int_as_float(p0.y);
        float v1 = __int_as_float(p1.y);
        a0 += v0 * bflo(u0.x); a1 += v0 * bfhi(u0.x);
        a2 += v0 * bflo(u0.y); a3 += v0 * bfhi(u0.y);
        a0 += v1 * bflo(u1.x); a1 += v1 * bfhi(u1.x);
        a2 += v1 * bflo(u1.y); a3 += v1 * bfhi(u1.y);
    }
    if (e < end) {
        int2 p = pairs[e];
        uint2 u = *(const uint2*)(x + (unsigned)(p.x * D + 4 * sl));
        float v = __int_as_float(p.y);
        a0 += v * bflo(u.x); a1 += v * bfhi(u.x);
        a2 += v * bflo(u.y); a3 += v * bfhi(u.y);
    }
    a0 += __shfl_xor(a0, 16); a0 += __shfl_xor(a0, 32);
    a1 += __shfl_xor(a1, 16); a1 += __shfl_xor(a1, 32);
    a2 += __shfl_xor(a2, 16); a2 += __shfl_xor(a2, 32);
    a3 += __shfl_xor(a3, 16); a3 += __shfl_xor(a3, 32);
    if (sub == 0) {
        float* o = out + (unsigned)(region * B * D + b * D + 4 * sl);
        float4 t = *(float4*)o;
        t.x += 0.25f * a0; t.y += 0.25f * a1;
        t.z += 0.25f * a2; t.w += 0.25f * a3;
        *(float4*)o = t;
    }
}

// ---------------------------------------------------------------------------
// Output init: raw table gathers (outputs 3..5, exact fp32) and the level-0
// contribution (0.25 * table rows) into outputs 0..2.
// ---------------------------------------------------------------------------
__global__ void gather_init(const float* __restrict__ ut,
                            const float* __restrict__ gt,
                            const int*   __restrict__ ui,
                            const int*   __restrict__ pg,
                            const int*   __restrict__ ng,
                            float*       __restrict__ out) {
    int i = blockIdx.x * blockDim.x + threadIdx.x;    // B*D threads
    if (i >= B * D) return;
    int b = i >> 6, d = i & 63;
    float u = ut[(size_t)ui[b] * D + d];
    float p = gt[(size_t)pg[b] * D + d];
    float n = gt[(size_t)ng[b] * D + d];
    const int S = B * D;
    out[0 * S + i] = 0.25f * u;
    out[1 * S + i] = 0.25f * p;
    out[2 * S + i] = 0.25f * n;
    out[3 * S + i] = u;
    out[4 * S + i] = p;
    out[5 * S + i] = n;
}

// ---------------------------------------------------------------------------
// Per-level accumulation of 0.25 * emb_l (bf16) at the gathered rows
// ---------------------------------------------------------------------------
__global__ void gather_acc(const unsigned short* __restrict__ emb,
                           const int*   __restrict__ ui,
                           const int*   __restrict__ pg,
                           const int*   __restrict__ ng,
                           float*       __restrict__ out) {
    int i = blockIdx.x * blockDim.x + threadIdx.x;    // B*D threads
    if (i >= B * D) return;
    int b = i >> 6, d = i & 63;
    const int S = B * D;
    out[0 * S + i] += 0.25f * bf2f(emb[(size_t)ui[b] * D + d]);
    out[1 * S + i] += 0.25f * bf2f(emb[((size_t)NUM_USER + pg[b]) * D + d]);
    out[2 * S + i] += 0.25f * bf2f(emb[((size_t)NUM_USER + ng[b]) * D + d]);
}

// ---------------------------------------------------------------------------
extern "C" void kernel_launch(void* const* d_in, const int* in_sizes, int n_in,
                              void* d_out, int out_size, void* d_ws, size_t ws_size,
                              hipStream_t stream) {
    const float* ut   = (const float*)d_in[0];
    const float* gt   = (const float*)d_in[1];
    const float* vals = (const float*)d_in[2];
    const int*   rows = (const int*)d_in[3];
    const int*   cols = (const int*)d_in[4];
    const int*   ui   = (const int*)d_in[5];
    const int*   pg   = (const int*)d_in[6];
    const int*   ng   = (const int*)d_in[7];
    float* out = (float*)d_out;

    // --- workspace layout (bf16 embeddings: 32 MB each) ---
    char* ws = (char*)d_ws;
    unsigned short* emb0 = (unsigned short*)ws;  ws += (size_t)NN * D * sizeof(unsigned short);
    unsigned short* emb1 = (unsigned short*)ws;  ws += (size_t)NN * D * sizeof(unsigned short);
    unsigned short* emb2 = (unsigned short*)ws;  ws += (size_t)NN * D * sizeof(unsigned short);
    int2*  pairs   = (int2*)ws;    ws += (size_t)E_EDGES * sizeof(int2);   // 32 MB
    int2*  stage   = (int2*)ws;    ws += (size_t)E_EDGES * sizeof(int2);   // 32 MB
    int*   row_ptr = (int*)ws;     ws += (size_t)(NN + 1) * sizeof(int);
    int*   bucketCounts = (int*)ws; ws += (size_t)NB_BUCKETS * sizeof(int);
    int*   bucketPtr    = (int*)ws; ws += (size_t)(NB_BUCKETS + 1) * sizeof(int);
    int*   cursorA      = (int*)ws; ws += (size_t)NB_BUCKETS * sizeof(int);

    // --- CSR build (once per call; reused for all 3 levels) ---
    hipMemsetAsync(bucketCounts, 0, (size_t)NB_BUCKETS * sizeof(int), stream);
    bucket_hist<<<(E_EDGES + CHUNK_EDGES - 1) / CHUNK_EDGES, 256, 0, stream>>>(rows, bucketCounts);
    bucket_scan<<<1, 256, 0, stream>>>(bucketCounts, bucketPtr, cursorA, row_ptr);
    bucket_phaseA<<<(E_EDGES + CHUNK_EDGES - 1) / CHUNK_EDGES, 256, 0, stream>>>(
        rows, cols, vals, cursorA, stage);
    bucket_phaseB<<<NB_BUCKETS, PB_THREADS, 0, stream>>>(bucketPtr, stage, pairs, row_ptr);

    // --- bf16 emb0 + outputs 3..5 + level-0 contribution ---
    {
        long long total4 = (long long)NN * D / 4;
        convert_tables<<<(int)((total4 + 255) / 256), 256, 0, stream>>>(ut, gt, emb0);
    }
    gather_init<<<(B * D + 255) / 256, 256, 0, stream>>>(ut, gt, ui, pg, ng, out);

    // --- propagation: 2 full levels (bf16) + output-sparse final level ---
    const int spmmBlocks = (NN + 3) / 4;   // 4 rows (waves) per 256-thread block
    spmm_pull_bf<<<spmmBlocks, 256, 0, stream>>>(row_ptr, pairs, emb0, emb1);
    gather_acc<<<(B * D + 255) / 256, 256, 0, stream>>>(emb1, ui, pg, ng, out);

    spmm_pull_bf<<<spmmBlocks, 256, 0, stream>>>(row_ptr, pairs, emb1, emb2);
    gather_acc<<<(B * D + 255) / 256, 256, 0, stream>>>(emb2, ui, pg, ng, out);

    // level 3: only the 24576 output rows, fused into the output accumulation
    final_pull<<<(3 * B + 3) / 4, 256, 0, stream>>>(row_ptr, pairs, emb2, ui, pg, ng, out);
}

// Round 4
// 492.009 us; speedup vs baseline: 1.0718x; 1.0718x over previous
//
#include <hip/hip_runtime.h>

#define NUM_USER  200000
#define NUM_GROUP 50000
#define NN        (NUM_USER + NUM_GROUP)   // 250000
#define E_EDGES   4000000
#define D         64
#define B         8192

#define BSHIFT       10                                     // 1024 rows / bucket
#define NB_BUCKETS   ((NN + (1 << BSHIFT) - 1) >> BSHIFT)   // 245
#define CHUNK_EDGES  4096                                   // edges per phase-A block
#define PB_THREADS   1024                                   // phase-B block size

// --- bf16 helpers (RNE; values are normal floats, no NaN path needed) ------
__device__ __forceinline__ float bf2f(unsigned short u) {
    return __uint_as_float(((unsigned int)u) << 16);
}
__device__ __forceinline__ unsigned short f2bf(float f) {
    unsigned int x = __float_as_uint(f);
    return (unsigned short)((x + 0x7FFFu + ((x >> 16) & 1u)) >> 16);
}
// packed-bf16 dword -> two floats (lo = even dim, hi = odd dim)
__device__ __forceinline__ float bflo(unsigned int u) { return __uint_as_float(u << 16); }
__device__ __forceinline__ float bfhi(unsigned int u) { return __uint_as_float(u & 0xFFFF0000u); }
__device__ __forceinline__ unsigned int pack2(float a, float b) {
    return (unsigned int)f2bf(a) | ((unsigned int)f2bf(b) << 16);
}

// ---------------------------------------------------------------------------
// Convert concat(user_table, group_table) fp32 -> bf16 emb0 (vectorized x4)
// ---------------------------------------------------------------------------
__global__ void __launch_bounds__(256)
convert_tables(const float* __restrict__ ut,
               const float* __restrict__ gt,
               unsigned short* __restrict__ embT) {
    const long long total4 = (long long)NN * D / 4;
    const long long user4  = (long long)NUM_USER * D / 4;
    long long i = (long long)blockIdx.x * blockDim.x + threadIdx.x;
    if (i >= total4) return;
    float4 v = (i < user4) ? ((const float4*)ut)[i] : ((const float4*)gt)[i - user4];
    ushort4 o;
    o.x = f2bf(v.x); o.y = f2bf(v.y); o.z = f2bf(v.z); o.w = f2bf(v.w);
    ((ushort4*)embT)[i] = o;
}

// ---------------------------------------------------------------------------
// Bucket histogram: LDS-aggregated 245-counter histogram per 4096-edge block,
// then ONE global atomic per (block, nonempty bucket).
// ---------------------------------------------------------------------------
__global__ void __launch_bounds__(256)
bucket_hist(const int* __restrict__ rows, int* __restrict__ bucketCounts) {
    __shared__ int cnt[NB_BUCKETS];
    const int t = threadIdx.x;
    if (t < NB_BUCKETS) cnt[t] = 0;
    __syncthreads();
    const int base = blockIdx.x * CHUNK_EDGES;
    #pragma unroll
    for (int k = 0; k < CHUNK_EDGES / 256; ++k) {
        int e = base + t + k * 256;
        if (e < E_EDGES) atomicAdd(&cnt[rows[e] >> BSHIFT], 1);
    }
    __syncthreads();
    if (t < NB_BUCKETS && cnt[t] > 0) atomicAdd(&bucketCounts[t], cnt[t]);
}

// ---------------------------------------------------------------------------
// Scan of the 245 bucket counts (single small block):
//   bucketPtr[b] = exclusive prefix, bucketPtr[245] = E,
//   cursorA[b]   = staging cursor init,
//   row_ptr[NN]  = E (per-row entries are written by phase B).
// ---------------------------------------------------------------------------
__global__ void __launch_bounds__(256)
bucket_scan(const int* __restrict__ bucketCounts,
            int* __restrict__ bucketPtr,
            int* __restrict__ cursorA,
            int* __restrict__ row_ptr) {
    __shared__ int s[256];
    const int t = threadIdx.x;
    int v = (t < NB_BUCKETS) ? bucketCounts[t] : 0;
    s[t] = v;
    __syncthreads();
    for (int off = 1; off < 256; off <<= 1) {
        int u = (t >= off) ? s[t - off] : 0;
        __syncthreads();
        s[t] += u;
        __syncthreads();
    }
    int excl = s[t] - v;
    if (t < NB_BUCKETS) { bucketPtr[t] = excl; cursorA[t] = excl; }
    if (t == 255) {
        bucketPtr[NB_BUCKETS] = s[255];   // == E
        row_ptr[NN] = s[255];
    }
}

// ---------------------------------------------------------------------------
// Phase A: LDS-aggregated bucket append (parallel cursor reservation,
// 16-lane subgroup copy-out).
// Staged element: { (row_in_bucket << 18) | col, bits(val) }.
// ---------------------------------------------------------------------------
__global__ void __launch_bounds__(256)
bucket_phaseA(const int*   __restrict__ rows,
              const int*   __restrict__ cols,
              const float* __restrict__ vals,
              int*         __restrict__ cursorA,
              int2*        __restrict__ stage) {
    __shared__ int  cnt[256];
    __shared__ int  off[256];
    __shared__ int  cur[256];
    __shared__ int  gbase[256];
    __shared__ int2 stg[CHUNK_EDGES];    // 32 KB
    const int t = threadIdx.x;
    cnt[t] = 0;
    __syncthreads();

    const int base = blockIdx.x * CHUNK_EDGES;
    int re[CHUNK_EDGES / 256];           // cache rows -> no second global read
    #pragma unroll
    for (int k = 0; k < CHUNK_EDGES / 256; ++k) {
        int e = base + t + k * 256;
        re[k] = (e < E_EDGES) ? rows[e] : -1;
        if (re[k] >= 0) atomicAdd(&cnt[re[k] >> BSHIFT], 1);
    }
    __syncthreads();

    // exclusive scan of cnt -> off (Hillis-Steele over 256)
    int v = cnt[t];
    off[t] = v;
    __syncthreads();
    for (int o = 1; o < 256; o <<= 1) {
        int u = (t >= o) ? off[t - o] : 0;
        __syncthreads();
        off[t] += u;
        __syncthreads();
    }
    int excl = off[t] - v;
    __syncthreads();
    off[t] = excl;
    cur[t] = excl;
    // parallel cursor reservation: one independent atomic per bucket
    if (t < NB_BUCKETS && v > 0) gbase[t] = atomicAdd(&cursorA[t], v);
    __syncthreads();

    // place into LDS staging
    #pragma unroll
    for (int k = 0; k < CHUNK_EDGES / 256; ++k) {
        int r = re[k];
        if (r >= 0) {
            int e = base + t + k * 256;
            int b = r >> BSHIFT;
            int slot = atomicAdd(&cur[b], 1);
            stg[slot] = make_int2(((r & ((1 << BSHIFT) - 1)) << 18) | cols[e],
                                  __float_as_int(vals[e]));
        }
    }
    __syncthreads();

    // copy runs out: 16-lane subgroups (mean run length ~17), no atomics here
    const int sg = t >> 4;    // 0..15
    const int sl = t & 15;
    for (int b = sg; b < NB_BUCKETS; b += 16) {
        int n = cnt[b];
        if (n == 0) continue;
        int gb = gbase[b];
        int lb = off[b];
        for (int i = sl; i < n; i += 16)
            stage[gb + i] = stg[lb + i];
    }
}

// ---------------------------------------------------------------------------
// Phase B: ONE block (1024 threads) per bucket.
//   pass 1: LDS histogram of row-in-bucket over the bucket's staged edges
//   scan  : 1024-wide LDS exclusive scan -> exact row_ptr for this bucket
//   pass 2: exact CSR placement via LDS row cursors
// ---------------------------------------------------------------------------
__global__ void __launch_bounds__(PB_THREADS)
bucket_phaseB(const int*  __restrict__ bucketPtr,
              const int2* __restrict__ stage,
              int2*       __restrict__ pairs,
              int*        __restrict__ row_ptr) {
    __shared__ int cnt[1 << BSHIFT];     // per-row counts, then cursors
    __shared__ int scn[1 << BSHIFT];     // scan workspace
    const int b = blockIdx.x;
    const int rowBase = b << BSHIFT;
    const int nRows = (NN - rowBase < (1 << BSHIFT)) ? (NN - rowBase) : (1 << BSHIFT);
    const int t = threadIdx.x;
    cnt[t] = 0;
    __syncthreads();

    const int s = bucketPtr[b];
    const int e = bucketPtr[b + 1];

    // pass 1: count rows within bucket
    for (int i = s + t; i < e; i += PB_THREADS)
        atomicAdd(&cnt[stage[i].x >> 18], 1);
    __syncthreads();

    // exclusive scan over 1024 counts (Hillis-Steele, 10 steps)
    int v = cnt[t];
    scn[t] = v;
    __syncthreads();
    for (int o = 1; o < PB_THREADS; o <<= 1) {
        int u = (t >= o) ? scn[t - o] : 0;
        __syncthreads();
        scn[t] += u;
        __syncthreads();
    }
    int excl = scn[t] - v;

    // emit row_ptr for this bucket and init LDS cursors
    if (t < nRows) row_ptr[rowBase + t] = s + excl;
    __syncthreads();
    cnt[t] = s + excl;
    __syncthreads();

    // pass 2: exact placement
    for (int i = s + t; i < e; i += PB_THREADS) {
        int2 p = stage[i];
        int rib = p.x >> 18;
        int col = p.x & 0x3FFFF;
        int slot = atomicAdd(&cnt[rib], 1);
        pairs[slot] = make_int2(col, p.y);
    }
}

// ---------------------------------------------------------------------------
// Pull-mode SpMM over bf16 embeddings: one wave per destination row.
//
// Key structure (latency-bound fix):
//  * the whole row's edge metadata (pairs) is loaded in ONE vmem instruction
//    (lane l -> pairs[start+l], zero-padded; deg>64 fallback below) and then
//    distributed from registers via __shfl -- no per-iteration pairs stall.
//  * eighth-wave gather: 8 lanes per edge, lane covers 8 dims via one 16-byte
//    uint4 load -> each gather instruction keeps 8 cache lines in flight.
//  * 1-deep software prefetch of the next group's gather before consuming
//    the current one -> the wave always has >=8 lines outstanding.
// fp32 accumulate, shfl_xor(8,16,32) cross-subgroup reduce, bf16 store.
// ---------------------------------------------------------------------------
__global__ void __launch_bounds__(256)
spmm_pull_bf(const int*  __restrict__ row_ptr,
             const int2* __restrict__ pairs,
             const unsigned short* __restrict__ x,
             unsigned short*       __restrict__ y) {
    const int row  = blockIdx.x * 4 + (threadIdx.x >> 6);   // 4 waves / block
    if (row >= NN) return;
    const int lane = threadIdx.x & 63;
    const int sub  = lane >> 3;          // eighth id 0..7 (edge slot)
    const int sl   = lane & 7;           // dims 8*sl .. 8*sl+7
    const int start = row_ptr[row];
    const int end   = row_ptr[row + 1];
    const int deg   = end - start;

    // one-instruction preload of up to 64 edges' (col, val)
    int2 pl = make_int2(0, 0);           // col 0 / val 0 -> contributes nothing
    if (lane < deg) pl = pairs[start + lane];
    const int degc = (deg > 64) ? 64 : deg;
    const int ng   = (degc + 7) >> 3;    // groups of 8 edges

    float a0 = 0.f, a1 = 0.f, a2 = 0.f, a3 = 0.f;
    float a4 = 0.f, a5 = 0.f, a6 = 0.f, a7 = 0.f;

    // pipelined gather loop (1-deep prefetch)
    int   col = __shfl(pl.x, sub);
    float v   = __int_as_float(__shfl(pl.y, sub));
    uint4 u   = *(const uint4*)(x + (unsigned)col * D + 8 * sl);
    for (int g = 0; g < ng; ++g) {
        int   ncol = col;
        float nv   = v;
        uint4 nu   = u;
        if (g + 1 < ng) {
            ncol = __shfl(pl.x, (g + 1) * 8 + sub);
            nv   = __int_as_float(__shfl(pl.y, (g + 1) * 8 + sub));
            nu   = *(const uint4*)(x + (unsigned)ncol * D + 8 * sl);
        }
        a0 += v * bflo(u.x); a1 += v * bfhi(u.x);
        a2 += v * bflo(u.y); a3 += v * bfhi(u.y);
        a4 += v * bflo(u.z); a5 += v * bfhi(u.z);
        a6 += v * bflo(u.w); a7 += v * bfhi(u.w);
        col = ncol; v = nv; u = nu;
    }

    // ultra-rare fallback: rows with more than 64 edges
    for (int e = start + 64 + sub; e < end; e += 8) {
        int2 p = pairs[e];
        uint4 uu = *(const uint4*)(x + (unsigned)p.x * D + 8 * sl);
        float vv = __int_as_float(p.y);
        a0 += vv * bflo(uu.x); a1 += vv * bfhi(uu.x);
        a2 += vv * bflo(uu.y); a3 += vv * bfhi(uu.y);
        a4 += vv * bflo(uu.z); a5 += vv * bfhi(uu.z);
        a6 += vv * bflo(uu.w); a7 += vv * bfhi(uu.w);
    }

    // reduce across the 8 subgroups (same dims live at same sl everywhere)
    a0 += __shfl_xor(a0, 8); a0 += __shfl_xor(a0, 16); a0 += __shfl_xor(a0, 32);
    a1 += __shfl_xor(a1, 8); a1 += __shfl_xor(a1, 16); a1 += __shfl_xor(a1, 32);
    a2 += __shfl_xor(a2, 8); a2 += __shfl_xor(a2, 16); a2 += __shfl_xor(a2, 32);
    a3 += __shfl_xor(a3, 8); a3 += __shfl_xor(a3, 16); a3 += __shfl_xor(a3, 32);
    a4 += __shfl_xor(a4, 8); a4 += __shfl_xor(a4, 16); a4 += __shfl_xor(a4, 32);
    a5 += __shfl_xor(a5, 8); a5 += __shfl_xor(a5, 16); a5 += __shfl_xor(a5, 32);
    a6 += __shfl_xor(a6, 8); a6 += __shfl_xor(a6, 16); a6 += __shfl_xor(a6, 32);
    a7 += __shfl_xor(a7, 8); a7 += __shfl_xor(a7, 16); a7 += __shfl_xor(a7, 32);

    if (sub == 0) {
        uint4 o;
        o.x = pack2(a0, a1); o.y = pack2(a2, a3);
        o.z = pack2(a4, a5); o.w = pack2(a6, a7);
        *(uint4*)(y + (unsigned)row * D + 8 * sl) = o;
    }
}

// ---------------------------------------------------------------------------
// Final level, output-sparse: one wave per OUTPUT SLOT (3*B slots), same
// preloaded eighth-wave structure; adds 0.25*sum into d_out.
// ---------------------------------------------------------------------------
__global__ void __launch_bounds__(256)
final_pull(const int*  __restrict__ row_ptr,
           const int2* __restrict__ pairs,
           const unsigned short* __restrict__ x,      // emb2 bf16
           const int*  __restrict__ ui,
           const int*  __restrict__ pg,
           const int*  __restrict__ ng_,
           float*      __restrict__ out) {
    const int slot = blockIdx.x * 4 + (threadIdx.x >> 6);   // 0 .. 3*B-1
    if (slot >= 3 * B) return;
    const int lane = threadIdx.x & 63;
    const int sub  = lane >> 3;
    const int sl   = lane & 7;
    const int region = slot / B;                 // 0=user, 1=pos, 2=neg
    const int b      = slot - region * B;
    int row;
    if (region == 0)      row = ui[b];
    else if (region == 1) row = NUM_USER + pg[b];
    else                  row = NUM_USER + ng_[b];

    const int start = row_ptr[row];
    const int end   = row_ptr[row + 1];
    const int deg   = end - start;

    int2 pl = make_int2(0, 0);
    if (lane < deg) pl = pairs[start + lane];
    const int degc = (deg > 64) ? 64 : deg;
    const int nG   = (degc + 7) >> 3;

    float a0 = 0.f, a1 = 0.f, a2 = 0.f, a3 = 0.f;
    float a4 = 0.f, a5 = 0.f, a6 = 0.f, a7 = 0.f;

    int   col = __shfl(pl.x, sub);
    float v   = __int_as_float(__shfl(pl.y, sub));
    uint4 u   = *(const uint4*)(x + (unsigned)col * D + 8 * sl);
    for (int g = 0; g < nG; ++g) {
        int   ncol = col;
        float nv   = v;
        uint4 nu   = u;
        if (g + 1 < nG) {
            ncol = __shfl(pl.x, (g + 1) * 8 + sub);
            nv   = __int_as_float(__shfl(pl.y, (g + 1) * 8 + sub));
            nu   = *(const uint4*)(x + (unsigned)ncol * D + 8 * sl);
        }
        a0 += v * bflo(u.x); a1 += v * bfhi(u.x);
        a2 += v * bflo(u.y); a3 += v * bfhi(u.y);
        a4 += v * bflo(u.z); a5 += v * bfhi(u.z);
        a6 += v * bflo(u.w); a7 += v * bfhi(u.w);
        col = ncol; v = nv; u = nu;
    }
    for (int e = start + 64 + sub; e < end; e += 8) {
        int2 p = pairs[e];
        uint4 uu = *(const uint4*)(x + (unsigned)p.x * D + 8 * sl);
        float vv = __int_as_float(p.y);
        a0 += vv * bflo(uu.x); a1 += vv * bfhi(uu.x);
        a2 += vv * bflo(uu.y); a3 += vv * bfhi(uu.y);
        a4 += vv * bflo(uu.z); a5 += vv * bfhi(uu.z);
        a6 += vv * bflo(uu.w); a7 += vv * bfhi(uu.w);
    }

    a0 += __shfl_xor(a0, 8); a0 += __shfl_xor(a0, 16); a0 += __shfl_xor(a0, 32);
    a1 += __shfl_xor(a1, 8); a1 += __shfl_xor(a1, 16); a1 += __shfl_xor(a1, 32);
    a2 += __shfl_xor(a2, 8); a2 += __shfl_xor(a2, 16); a2 += __shfl_xor(a2, 32);
    a3 += __shfl_xor(a3, 8); a3 += __shfl_xor(a3, 16); a3 += __shfl_xor(a3, 32);
    a4 += __shfl_xor(a4, 8); a4 += __shfl_xor(a4, 16); a4 += __shfl_xor(a4, 32);
    a5 += __shfl_xor(a5, 8); a5 += __shfl_xor(a5, 16); a5 += __shfl_xor(a5, 32);
    a6 += __shfl_xor(a6, 8); a6 += __shfl_xor(a6, 16); a6 += __shfl_xor(a6, 32);
    a7 += __shfl_xor(a7, 8); a7 += __shfl_xor(a7, 16); a7 += __shfl_xor(a7, 32);

    if (sub == 0) {
        float* o = out + (unsigned)(region * B * D + b * D + 8 * sl);
        float4 t0 = *(float4*)o;
        float4 t1 = *(float4*)(o + 4);
        t0.x += 0.25f * a0; t0.y += 0.25f * a1;
        t0.z += 0.25f * a2; t0.w += 0.25f * a3;
        t1.x += 0.25f * a4; t1.y += 0.25f * a5;
        t1.z += 0.25f * a6; t1.w += 0.25f * a7;
        *(float4*)o = t0;
        *(float4*)(o + 4) = t1;
    }
}

// ---------------------------------------------------------------------------
// Output init: raw table gathers (outputs 3..5, exact fp32) and the level-0
// contribution (0.25 * table rows) into outputs 0..2.
// ---------------------------------------------------------------------------
__global__ void gather_init(const float* __restrict__ ut,
                            const float* __restrict__ gt,
                            const int*   __restrict__ ui,
                            const int*   __restrict__ pg,
                            const int*   __restrict__ ng,
                            float*       __restrict__ out) {
    int i = blockIdx.x * blockDim.x + threadIdx.x;    // B*D threads
    if (i >= B * D) return;
    int b = i >> 6, d = i & 63;
    float u = ut[(size_t)ui[b] * D + d];
    float p = gt[(size_t)pg[b] * D + d];
    float n = gt[(size_t)ng[b] * D + d];
    const int S = B * D;
    out[0 * S + i] = 0.25f * u;
    out[1 * S + i] = 0.25f * p;
    out[2 * S + i] = 0.25f * n;
    out[3 * S + i] = u;
    out[4 * S + i] = p;
    out[5 * S + i] = n;
}

// ---------------------------------------------------------------------------
// Per-level accumulation of 0.25 * emb_l (bf16) at the gathered rows
// ---------------------------------------------------------------------------
__global__ void gather_acc(const unsigned short* __restrict__ emb,
                           const int*   __restrict__ ui,
                           const int*   __restrict__ pg,
                           const int*   __restrict__ ng,
                           float*       __restrict__ out) {
    int i = blockIdx.x * blockDim.x + threadIdx.x;    // B*D threads
    if (i >= B * D) return;
    int b = i >> 6, d = i & 63;
    const int S = B * D;
    out[0 * S + i] += 0.25f * bf2f(emb[(size_t)ui[b] * D + d]);
    out[1 * S + i] += 0.25f * bf2f(emb[((size_t)NUM_USER + pg[b]) * D + d]);
    out[2 * S + i] += 0.25f * bf2f(emb[((size_t)NUM_USER + ng[b]) * D + d]);
}

// ---------------------------------------------------------------------------
extern "C" void kernel_launch(void* const* d_in, const int* in_sizes, int n_in,
                              void* d_out, int out_size, void* d_ws, size_t ws_size,
                              hipStream_t stream) {
    const float* ut   = (const float*)d_in[0];
    const float* gt   = (const float*)d_in[1];
    const float* vals = (const float*)d_in[2];
    const int*   rows = (const int*)d_in[3];
    const int*   cols = (const int*)d_in[4];
    const int*   ui   = (const int*)d_in[5];
    const int*   pg   = (const int*)d_in[6];
    const int*   ng   = (const int*)d_in[7];
    float* out = (float*)d_out;

    // --- workspace layout (bf16 embeddings: 32 MB each) ---
    char* ws = (char*)d_ws;
    unsigned short* emb0 = (unsigned short*)ws;  ws += (size_t)NN * D * sizeof(unsigned short);
    unsigned short* emb1 = (unsigned short*)ws;  ws += (size_t)NN * D * sizeof(unsigned short);
    unsigned short* emb2 = (unsigned short*)ws;  ws += (size_t)NN * D * sizeof(unsigned short);
    int2*  pairs   = (int2*)ws;    ws += (size_t)E_EDGES * sizeof(int2);   // 32 MB
    int2*  stage   = (int2*)ws;    ws += (size_t)E_EDGES * sizeof(int2);   // 32 MB
    int*   row_ptr = (int*)ws;     ws += (size_t)(NN + 1) * sizeof(int);
    int*   bucketCounts = (int*)ws; ws += (size_t)NB_BUCKETS * sizeof(int);
    int*   bucketPtr    = (int*)ws; ws += (size_t)(NB_BUCKETS + 1) * sizeof(int);
    int*   cursorA      = (int*)ws; ws += (size_t)NB_BUCKETS * sizeof(int);

    // --- CSR build (once per call; reused for all 3 levels) ---
    hipMemsetAsync(bucketCounts, 0, (size_t)NB_BUCKETS * sizeof(int), stream);
    bucket_hist<<<(E_EDGES + CHUNK_EDGES - 1) / CHUNK_EDGES, 256, 0, stream>>>(rows, bucketCounts);
    bucket_scan<<<1, 256, 0, stream>>>(bucketCounts, bucketPtr, cursorA, row_ptr);
    bucket_phaseA<<<(E_EDGES + CHUNK_EDGES - 1) / CHUNK_EDGES, 256, 0, stream>>>(
        rows, cols, vals, cursorA, stage);
    bucket_phaseB<<<NB_BUCKETS, PB_THREADS, 0, stream>>>(bucketPtr, stage, pairs, row_ptr);

    // --- bf16 emb0 + outputs 3..5 + level-0 contribution ---
    {
        long long total4 = (long long)NN * D / 4;
        convert_tables<<<(int)((total4 + 255) / 256), 256, 0, stream>>>(ut, gt, emb0);
    }
    gather_init<<<(B * D + 255) / 256, 256, 0, stream>>>(ut, gt, ui, pg, ng, out);

    // --- propagation: 2 full levels (bf16) + output-sparse final level ---
    const int spmmBlocks = (NN + 3) / 4;   // 4 rows (waves) per 256-thread block
    spmm_pull_bf<<<spmmBlocks, 256, 0, stream>>>(row_ptr, pairs, emb0, emb1);
    gather_acc<<<(B * D + 255) / 256, 256, 0, stream>>>(emb1, ui, pg, ng, out);

    spmm_pull_bf<<<spmmBlocks, 256, 0, stream>>>(row_ptr, pairs, emb1, emb2);
    gather_acc<<<(B * D + 255) / 256, 256, 0, stream>>>(emb2, ui, pg, ng, out);

    // level 3: only the 24576 output rows, fused into the output accumulation
    final_pull<<<(3 * B + 3) / 4, 256, 0, stream>>>(row_ptr, pairs, emb2, ui, pg, ng, out);
}